// Round 1
// baseline (14075.000 us; speedup 1.0000x reference)
//
#include <hip/hip_runtime.h>
#include <math.h>

// MPGRUImputer on MI355X. B=8, F=1, N=1024, T=128, H=64, ORDER=2.
// Per step: TWO fused kernels (was four):
//   kphA: diffusion(xh) x {A_f,A_f^2,A_b,A_b^2} -> LDS, conv r/u, build xc/yct
//   kphB: diffusion(xc) -> LDS, conv c, h update, x_hat/preds/states, stage next xh
// 512 blocks x 256 thr (2 blocks/CU -> 2 waves/SIMD for latency hiding).
// Diffused z stays in LDS (stride 424 u16 => 2-way LDS bank aliasing, free).

typedef unsigned short u16;
typedef unsigned int u32;
typedef short bf16x8 __attribute__((ext_vector_type(8)));  // 8 bf16 = 4 VGPRs
typedef float f32x4 __attribute__((ext_vector_type(4)));

#define MFMA16(a, b, c) __builtin_amdgcn_mfma_f32_16x16x32_bf16((a), (b), (c), 0, 0, 0)

#define Bz 8
#define Tt 128
#define Hh 64
#define KC 416   // padded conv K (weight row stride): 66 hi + 66 lo + 4*66 z + 20 pad
#define KD 136   // direct-channel global row stride (ch 0..131 + 4 pad)
#define KL 424   // LDS conv-B row stride in u16 (2-way bank aliasing on ds_read_b128)
#define CP 80    // padded diffusion M rows per batch (66 valid)

static __device__ __forceinline__ u16 f2b(float f) {  // RNE f32->bf16
  u32 u = __float_as_uint(f);
  u = (u + 0x7FFFu + ((u >> 16) & 1u)) >> 16;
  return (u16)u;
}
static __device__ __forceinline__ float b2f(u16 s) { return __uint_as_float(((u32)s) << 16); }
static __device__ __forceinline__ bf16x8 ld8(const u16* p) { return *reinterpret_cast<const bf16x8*>(p); }
static __device__ __forceinline__ void st2f(u16* p, float a, float b) {
  *reinterpret_cast<u32*>(p) = (u32)f2b(a) | ((u32)f2b(b) << 16);
}
static __device__ __forceinline__ void st2u(u16* p, u16 a, u16 b) {
  *reinterpret_cast<u32*>(p) = (u32)a | ((u32)b << 16);
}
static __device__ __forceinline__ float sigm(float x) { return 1.f / (1.f + __expf(-x)); }
static __device__ __forceinline__ float tanh_f(float x) {
  x = fminf(fmaxf(x, -15.f), 15.f);
  float e = __expf(2.f * x);
  return (e - 1.f) / (e + 1.f);
}

// ---- setup: row/col sums of adj -> 1/(sum+eps) ------------------------------
__global__ __launch_bounds__(256) void ksums(const float* adj, float* rinv, float* cinv) {
  int id = blockIdx.x * 256 + threadIdx.x;  // 0..2047
  if (id < 1024) {
    int w = id;  // column sum (coalesced across threads)
    float s = 0.f;
    for (int v = 0; v < 1024; ++v) s += adj[v * 1024 + w];
    cinv[w] = 1.f / (s + 1e-8f);
  } else {
    int w = id - 1024;  // row sum
    float s = 0.f;
    for (int v = 0; v < 1024; ++v) s += adj[w * 1024 + v];
    rinv[w] = 1.f / (s + 1e-8f);
  }
}

// ---- setup: build bf16 operators A_f, A_b (+ transposed copies for A^2 GEMM)
// Aops layout: [op][w][v], op: 0=A_f, 1=A_f^2, 2=A_b, 3=A_b^2
__global__ __launch_bounds__(256) void kmakeops(const float* adj, const float* rinv, const float* cinv,
                                                u16* Aops, u16* supft, u16* supbt) {
  int idx = blockIdx.x * 256 + threadIdx.x;  // w*1024+v, v coalesced
  int w = idx >> 10, v = idx & 1023;
  float a = adj[idx];
  u16 f = f2b(a * rinv[w]);   // A_f[w][v]
  u16 bb = f2b(a * cinv[v]);  // = A_b[v][w]
  Aops[idx] = f;
  supft[v * 1024 + w] = f;                // A_f^T[v][w]
  supbt[idx] = bb;                        // A_b^T[w][v]
  Aops[2 * 1048576 + v * 1024 + w] = bb;  // A_b[v][w]
}

// ---- setup: A^2 via bf16 MFMA: out[w][v] = sum_u A[w][u]*A[u][v] ------------
__global__ __launch_bounds__(256) void kA2(u16* Aops, const u16* supft, const u16* supbt) {
  int wg = blockIdx.x;  // 2 * 8 * 8 = 128
  int o2 = wg & 1, mt = (wg >> 1) & 7, ntt = (wg >> 4) & 7;
  const u16* Ab = Aops + (o2 ? 2 * 1048576 : 0);
  const u16* Bb = o2 ? supbt : supft;
  u16* Ob = Aops + (o2 ? 3 * 1048576 : 1048576);
  int tid = threadIdx.x, wave = tid >> 6, lane = tid & 63, l15 = lane & 15, quad = lane >> 4;
  int mbase = mt * 128 + wave * 32;
  f32x4 acc[2][8];
#pragma unroll
  for (int m = 0; m < 2; ++m)
#pragma unroll
    for (int j = 0; j < 8; ++j) acc[m][j] = (f32x4){0.f, 0.f, 0.f, 0.f};
  for (int k = 0; k < 1024; k += 32) {
    int kq = k + quad * 8;
    bf16x8 av[2], bv[8];
#pragma unroll
    for (int m = 0; m < 2; ++m) av[m] = ld8(Ab + (mbase + m * 16 + l15) * 1024 + kq);
#pragma unroll
    for (int j = 0; j < 8; ++j) bv[j] = ld8(Bb + (ntt * 128 + j * 16 + l15) * 1024 + kq);
#pragma unroll
    for (int m = 0; m < 2; ++m)
#pragma unroll
      for (int j = 0; j < 8; ++j) acc[m][j] = MFMA16(av[m], bv[j], acc[m][j]);
  }
#pragma unroll
  for (int m = 0; m < 2; ++m)
#pragma unroll
    for (int j = 0; j < 8; ++j) {
      int v = ntt * 128 + j * 16 + l15;
#pragma unroll
      for (int i = 0; i < 4; ++i) {
        int w = mbase + m * 16 + quad * 4 + i;
        Ob[w * 1024 + v] = f2b(acc[m][j][i]);
      }
    }
}

// ---- setup: pack weights to bf16, K=416 layout ------------------------------
__global__ __launch_bounds__(256) void kpackw(const float* Wr, const float* Wu, const float* Wc,
                                              u16* Wrup, u16* Wcp) {
  int idx = blockIdx.x * 256 + threadIdx.x;  // 192*416 = 79872
  int r = idx / KC, k = idx % KC;
  if (r >= 192) return;
  float wv = 0.f;
  if (k < 396) {
    int c = (k < 66) ? k : (k - 66);  // hi block: c=k; lo block + diffused: c=k-66
    if (r < 64) wv = Wr[r * 330 + c];
    else if (r < 128) wv = Wu[(r - 64) * 330 + c];
    else wv = Wc[(r - 128) * 330 + c];
  }
  if (r < 128) Wrup[r * KC + k] = f2b(wv);
  else Wcp[(r - 128) * KC + k] = f2b(wv);
}

// ---- setup: t=0 state, outputs, staging buffers, zero pads ------------------
__global__ __launch_bounds__(256) void kstep0(const float* x, const int* mask, const float* bout,
                                              float* h, float* states, float* preds,
                                              u16* xh, u16* xc, u16* zct) {
  int idx = blockIdx.x * 256 + threadIdx.x;  // b*65536 + o*1024 + n
  int b = idx >> 16, o = (idx >> 10) & 63, n = idx & 1023;
  int hidx = (b * 64 + o) * 1024 + n;
  h[hidx] = 0.f;
  states[(size_t)hidx * 128] = 0.f;  // states[t=0] = h0 = 0
  xh[(b * CP + 2 + o) * 1024 + n] = 0;
  u16* zr = zct + (size_t)(b * 1024 + n) * KD;
  zr[2 + o] = 0;   // h hi
  zr[68 + o] = 0;  // h lo
  if (o == 0) {
    int xi = (b * 1024 + n) * 128;
    float xhat = bout[0];  // Wout . 0 + bout
    int mv = mask[xi];
    float xin = mv ? x[xi] : xhat;
    preds[xi] = xhat;
    u16 hi = f2b(xin), lo = f2b(xin - b2f(hi));
    xh[(b * CP + 0) * 1024 + n] = hi;
    xh[(b * CP + 1) * 1024 + n] = f2b((float)mv);
    zr[0] = hi; zr[1] = f2b((float)mv); zr[66] = lo; zr[67] = 0;
  } else if (o == 1) {
    for (int j = 66; j < 80; ++j) {  // zero pad rows of diffusion A-operands
      xh[(b * CP + j) * 1024 + n] = 0;
      xc[(b * CP + j) * 1024 + n] = 0;
    }
  }
}

// ---- phase A (fused): diffusion(xh) -> LDS; conv r,u; write u, xc, yct ------
// grid 512 = b*64 + nt (16 nodes per block); wave == diffusion op
__global__ __launch_bounds__(256) void kphA(const u16* __restrict__ xh, const u16* __restrict__ Aops,
                                            const u16* __restrict__ zct, const u16* __restrict__ Wrup,
                                            const float* br, const float* bu,
                                            const float* __restrict__ h, float* __restrict__ ubuf,
                                            u16* __restrict__ xc, u16* __restrict__ yct) {
  __shared__ u16 zl[16][KL];
  int wg = blockIdx.x;
  int b = wg >> 6, nt = wg & 63;
  int tid = threadIdx.x, wave = tid >> 6, lane = tid & 63, l15 = lane & 15, quad = lane >> 4;
  // stage direct channels 0..131 from global (as u32 pairs) + zero pad 396..415
  for (int i = tid; i < 16 * 76; i += 256) {
    int n = i / 76, c = i - n * 76;
    u32* dst = (u32*)zl[n];
    if (c < 66) dst[c] = ((const u32*)(zct + (size_t)(b * 1024 + nt * 16 + n) * KD))[c];
    else dst[132 + c] = 0;  // u32 198..207 = ch 396..415
  }
  // diffusion: z_op[c][w] = sum_v xh[b][c][v] * A_op[w][v];  wave = op
  {
    const u16* Zb = xh + b * CP * 1024;
    const u16* Ab = Aops + (wave << 20);
    int col = nt * 16 + l15;
    f32x4 acc[5];
#pragma unroll
    for (int m = 0; m < 5; ++m) acc[m] = (f32x4){0.f, 0.f, 0.f, 0.f};
    for (int k = 0; k < 1024; k += 32) {
      int kq = k + quad * 8;
      bf16x8 bv = ld8(Ab + col * 1024 + kq);
      bf16x8 av[5];
#pragma unroll
      for (int m = 0; m < 5; ++m) av[m] = ld8(Zb + (m * 16 + l15) * 1024 + kq);
#pragma unroll
      for (int m = 0; m < 5; ++m) acc[m] = MFMA16(av[m], bv, acc[m]);
    }
    int cbase = 132 + wave * 66;
    u16* orow = zl[l15] + cbase;  // D col = l15 = local node
#pragma unroll
    for (int m = 0; m < 5; ++m) {
      int c0 = m * 16 + quad * 4;  // D row = channel
      if (c0 < 64) {
        st2f(orow + c0, acc[m][0], acc[m][1]);
        st2f(orow + c0 + 2, acc[m][2], acc[m][3]);
      } else if (c0 == 64) {  // m==4, quad==0: channels 64,65 only
        st2f(orow + 64, acc[m][0], acc[m][1]);
      }
    }
  }
  __syncthreads();
  // conv r,u: [128 out x 416 K] x [16 nodes], B from LDS
  {
    int obase = wave * 32;
    f32x4 acc[2];
    acc[0] = (f32x4){0.f, 0.f, 0.f, 0.f};
    acc[1] = (f32x4){0.f, 0.f, 0.f, 0.f};
    for (int k = 0; k < KC; k += 32) {
      int kq = k + quad * 8;
      bf16x8 bv = ld8(zl[l15] + kq);
      bf16x8 av0 = ld8(Wrup + (obase + l15) * KC + kq);
      bf16x8 av1 = ld8(Wrup + (obase + 16 + l15) * KC + kq);
      acc[0] = MFMA16(av0, bv, acc[0]);
      acc[1] = MFMA16(av1, bv, acc[1]);
    }
    int n = nt * 16 + l15;
#pragma unroll
    for (int m = 0; m < 2; ++m) {
      int o0 = obase + m * 16 + quad * 4;
      if (o0 < 64) {  // r gate -> r*h into xc (diff A-op) and yct hi/lo (conv B-op)
        u16 hi[4], lo[4];
#pragma unroll
        for (int i = 0; i < 4; ++i) {
          float s = sigm(acc[m][i] + br[o0 + i]);
          float rh = s * h[(b * 64 + o0 + i) * 1024 + n];
          hi[i] = f2b(rh);
          lo[i] = f2b(rh - b2f(hi[i]));
          xc[(b * CP + 2 + o0 + i) * 1024 + n] = hi[i];
        }
        u16* yr = yct + (size_t)(b * 1024 + n) * KD;
        st2u(yr + 2 + o0, hi[0], hi[1]);
        st2u(yr + 4 + o0, hi[2], hi[3]);
        st2u(yr + 68 + o0, lo[0], lo[1]);
        st2u(yr + 70 + o0, lo[2], lo[3]);
      } else {  // u gate
#pragma unroll
        for (int i = 0; i < 4; ++i)
          ubuf[(b * 64 + o0 - 64 + i) * 1024 + n] = sigm(acc[m][i] + bu[o0 - 64 + i]);
      }
    }
  }
  if (tid < 16) {  // copy x_in/mask channels into phase-B buffers
    int n = nt * 16 + tid;
    const u16* zr = zl[tid];
    u16* yr = yct + (size_t)(b * 1024 + n) * KD;
    yr[0] = zr[0]; yr[1] = zr[1]; yr[66] = zr[66]; yr[67] = zr[67];
    xc[(b * CP + 0) * 1024 + n] = zr[0];
    xc[(b * CP + 1) * 1024 + n] = zr[1];
  }
}

// ---- phase B (fused): diffusion(xc) -> LDS; conv c; h update; x_hat ---------
__global__ __launch_bounds__(256) void kphB(const u16* __restrict__ xc, const u16* __restrict__ Aops,
                                            const u16* __restrict__ yct, const u16* __restrict__ Wcp,
                                            const float* bc, const float* __restrict__ ubuf,
                                            float* __restrict__ h, const float* __restrict__ x,
                                            const int* __restrict__ mask, const float* Wout,
                                            const float* bout, float* __restrict__ preds,
                                            float* __restrict__ states, u16* __restrict__ xh,
                                            u16* __restrict__ zct, int t) {
  __shared__ u16 yl[16][KL];
  __shared__ float hbuf[64][17];
  int wg = blockIdx.x;
  int b = wg >> 6, nt = wg & 63;
  int tid = threadIdx.x, wave = tid >> 6, lane = tid & 63, l15 = lane & 15, quad = lane >> 4;
  for (int i = tid; i < 16 * 76; i += 256) {
    int n = i / 76, c = i - n * 76;
    u32* dst = (u32*)yl[n];
    if (c < 66) dst[c] = ((const u32*)(yct + (size_t)(b * 1024 + nt * 16 + n) * KD))[c];
    else dst[132 + c] = 0;
  }
  // diffusion of xc
  {
    const u16* Zb = xc + b * CP * 1024;
    const u16* Ab = Aops + (wave << 20);
    int col = nt * 16 + l15;
    f32x4 acc[5];
#pragma unroll
    for (int m = 0; m < 5; ++m) acc[m] = (f32x4){0.f, 0.f, 0.f, 0.f};
    for (int k = 0; k < 1024; k += 32) {
      int kq = k + quad * 8;
      bf16x8 bv = ld8(Ab + col * 1024 + kq);
      bf16x8 av[5];
#pragma unroll
      for (int m = 0; m < 5; ++m) av[m] = ld8(Zb + (m * 16 + l15) * 1024 + kq);
#pragma unroll
      for (int m = 0; m < 5; ++m) acc[m] = MFMA16(av[m], bv, acc[m]);
    }
    int cbase = 132 + wave * 66;
    u16* orow = yl[l15] + cbase;
#pragma unroll
    for (int m = 0; m < 5; ++m) {
      int c0 = m * 16 + quad * 4;
      if (c0 < 64) {
        st2f(orow + c0, acc[m][0], acc[m][1]);
        st2f(orow + c0 + 2, acc[m][2], acc[m][3]);
      } else if (c0 == 64) {
        st2f(orow + 64, acc[m][0], acc[m][1]);
      }
    }
  }
  __syncthreads();
  // conv c: [64 out x 416 K] x [16 nodes]; wave covers 16 outputs
  f32x4 acc = (f32x4){0.f, 0.f, 0.f, 0.f};
  for (int k = 0; k < KC; k += 32) {
    int kq = k + quad * 8;
    bf16x8 bv = ld8(yl[l15] + kq);
    bf16x8 av = ld8(Wcp + (wave * 16 + l15) * KC + kq);
    acc = MFMA16(av, bv, acc);
  }
  int t1 = t + 1;
  int n = nt * 16 + l15;
  int o0 = wave * 16 + quad * 4;
  u16 hi[4], lo[4];
#pragma unroll
  for (int i = 0; i < 4; ++i) {
    int o = o0 + i;
    float c = tanh_f(acc[i] + bc[o]);
    int idx = (b * 64 + o) * 1024 + n;
    float u = ubuf[idx], hp = h[idx];
    float hn = u * hp + (1.f - u) * c;
    h[idx] = hn;
    hbuf[o][l15] = hn;
    hi[i] = f2b(hn);
    lo[i] = f2b(hn - b2f(hi[i]));
    if (t1 < Tt) {
      states[(size_t)idx * 128 + t1] = hn;
      xh[(b * CP + 2 + o) * 1024 + n] = hi[i];
    }
  }
  if (t1 < Tt) {
    u16* zr = zct + (size_t)(b * 1024 + n) * KD;
    st2u(zr + 2 + o0, hi[0], hi[1]);
    st2u(zr + 4 + o0, hi[2], hi[3]);
    st2u(zr + 68 + o0, lo[0], lo[1]);
    st2u(zr + 70 + o0, lo[2], lo[3]);
  }
  __syncthreads();
  if (tid < 16 && t1 < Tt) {
    int nn = nt * 16 + tid;
    float xhat = bout[0];
#pragma unroll
    for (int o = 0; o < 64; ++o) xhat += Wout[o] * hbuf[o][tid];
    int xi = (b * 1024 + nn) * 128 + t1;
    int mv = mask[xi];
    float xin = mv ? x[xi] : xhat;
    preds[xi] = xhat;
    u16 hi2 = f2b(xin), lo2 = f2b(xin - b2f(hi2));
    xh[(b * CP + 0) * 1024 + nn] = hi2;
    xh[(b * CP + 1) * 1024 + nn] = f2b((float)mv);
    u16* zr = zct + (size_t)(b * 1024 + nn) * KD;
    zr[0] = hi2; zr[1] = f2b((float)mv); zr[66] = lo2; zr[67] = 0;
  }
}

extern "C" void kernel_launch(void* const* d_in, const int* in_sizes, int n_in,
                              void* d_out, int out_size, void* d_ws, size_t ws_size,
                              hipStream_t stream) {
  const float* x = (const float*)d_in[0];
  const int* mask = (const int*)d_in[1];
  const float* adj = (const float*)d_in[2];
  const float* Wr = (const float*)d_in[3];
  const float* br = (const float*)d_in[4];
  const float* Wu = (const float*)d_in[5];
  const float* bu = (const float*)d_in[6];
  const float* Wc = (const float*)d_in[7];
  const float* bc = (const float*)d_in[8];
  const float* Wout = (const float*)d_in[9];
  const float* bout = (const float*)d_in[10];

  float* preds = (float*)d_out;                  // [8,1,1024,128]
  float* states = preds + 8 * 1024 * 128;        // [1,8,64,1024,128]

  // workspace carve-up (bf16 buffers as u16; all MFMA-load bases 16B aligned)
  u16* Aops = (u16*)d_ws;                        // [4][1024][1024]
  u16* supft = Aops + 4 * 1048576;               // A_f^T
  u16* supbt = supft + 1048576;                  // A_b^T
  float* rinv = (float*)(supbt + 1048576);
  float* cinv = rinv + 1024;
  u16* xh = (u16*)(cinv + 1024);                 // [8][80][1024] diffusion A-op, phase A
  u16* xc = xh + Bz * CP * 1024;                 // [8][80][1024] phase B
  u16* zct = xc + Bz * CP * 1024;                // [8][1024][136] direct ch, phase A
  u16* yct = zct + Bz * 1024 * KD;               // [8][1024][136] phase B
  u16* Wrup = yct + Bz * 1024 * KD;              // [128][416]
  u16* Wcp = Wrup + 128 * KC;                    // [64][416]
  float* ubuf = (float*)(Wcp + 64 * KC);         // [8][64][1024]
  float* h = ubuf + Bz * 64 * 1024;              // [8][64][1024]

  ksums<<<8, 256, 0, stream>>>(adj, rinv, cinv);
  kmakeops<<<4096, 256, 0, stream>>>(adj, rinv, cinv, Aops, supft, supbt);
  kA2<<<128, 256, 0, stream>>>(Aops, supft, supbt);
  kpackw<<<312, 256, 0, stream>>>(Wr, Wu, Wc, Wrup, Wcp);
  kstep0<<<2048, 256, 0, stream>>>(x, mask, bout, h, states, preds, xh, xc, zct);

  for (int t = 0; t < Tt; ++t) {
    kphA<<<512, 256, 0, stream>>>(xh, Aops, zct, Wrup, br, bu, h, ubuf, xc, yct);
    kphB<<<512, 256, 0, stream>>>(xc, Aops, yct, Wcp, bc, ubuf, h, x, mask, Wout, bout,
                                  preds, states, xh, zct, t);
  }
}

// Round 2
// 10088.506 us; speedup vs baseline: 1.3952x; 1.3952x over previous
//
#include <hip/hip_runtime.h>
#include <math.h>

// MPGRUImputer on MI355X. B=8, F=1, N=1024, T=128, H=64, ORDER=2.
// Two fused kernels per step, FAT tiles + K-split (8 waves/block = 2 waves/SIMD):
//   kphA: diffusion(xh) -> LDS zl, conv r/u (B from LDS), write ubuf + xc
//   kphB: diffusion(xc) -> LDS yl, conv c, h update, x_hat/preds/states, stage xh
// Phase boundaries carry only coalesced [ch][node] bf16 buffers (xh/xc with
// hi rows 0..79 and lo rows 80..145); direct channels transposed into LDS at
// kernel start. Diffused channels never touch global.

typedef unsigned short u16;
typedef unsigned int u32;
typedef short bf16x8 __attribute__((ext_vector_type(8)));  // 8 bf16 = 4 VGPRs
typedef float f32x4 __attribute__((ext_vector_type(4)));

#define MFMA16(a, b, c) __builtin_amdgcn_mfma_f32_16x16x32_bf16((a), (b), (c), 0, 0, 0)

#define Bz 8
#define Tt 128
#define Hh 64
#define KC 416   // padded conv K (weight row stride): 66 hi + 66 lo + 4*66 z + 20 pad
#define KL 424   // LDS conv-B row stride in u16 (848B: 16B-aligned, low conflict)
#define CP 148   // xh/xc rows: 0..65 hi, 66..79 zero pad (diffusion M=80), 80..145 lo
#define ZLB (32 * KL * 2)              // 27136 B
#define SCRB (4 * 64 * 44 * 4)        // 45056 B  f32 scratch [4][64][44]

static __device__ __forceinline__ u16 f2b(float f) {  // RNE f32->bf16
  u32 u = __float_as_uint(f);
  u = (u + 0x7FFFu + ((u >> 16) & 1u)) >> 16;
  return (u16)u;
}
static __device__ __forceinline__ float b2f(u16 s) { return __uint_as_float(((u32)s) << 16); }
static __device__ __forceinline__ bf16x8 ld8(const u16* p) { return *reinterpret_cast<const bf16x8*>(p); }
static __device__ __forceinline__ void st2f(u16* p, float a, float b) {
  *reinterpret_cast<u32*>(p) = (u32)f2b(a) | ((u32)f2b(b) << 16);
}
static __device__ __forceinline__ float sigm(float x) { return 1.f / (1.f + __expf(-x)); }
static __device__ __forceinline__ float tanh_f(float x) {
  x = fminf(fmaxf(x, -15.f), 15.f);
  float e = __expf(2.f * x);
  return (e - 1.f) / (e + 1.f);
}

// ---- setup: row/col sums of adj -> 1/(sum+eps) ------------------------------
__global__ __launch_bounds__(256) void ksums(const float* adj, float* rinv, float* cinv) {
  int id = blockIdx.x * 256 + threadIdx.x;  // 0..2047
  if (id < 1024) {
    int w = id;  // column sum (coalesced across threads)
    float s = 0.f;
    for (int v = 0; v < 1024; ++v) s += adj[v * 1024 + w];
    cinv[w] = 1.f / (s + 1e-8f);
  } else {
    int w = id - 1024;  // row sum
    float s = 0.f;
    for (int v = 0; v < 1024; ++v) s += adj[w * 1024 + v];
    rinv[w] = 1.f / (s + 1e-8f);
  }
}

// ---- setup: build bf16 operators A_f, A_b (+ transposed copies for A^2 GEMM)
// Aops layout: [op][w][v], op: 0=A_f, 1=A_f^2, 2=A_b, 3=A_b^2
__global__ __launch_bounds__(256) void kmakeops(const float* adj, const float* rinv, const float* cinv,
                                                u16* Aops, u16* supft, u16* supbt) {
  int idx = blockIdx.x * 256 + threadIdx.x;  // w*1024+v, v coalesced
  int w = idx >> 10, v = idx & 1023;
  float a = adj[idx];
  u16 f = f2b(a * rinv[w]);   // A_f[w][v]
  u16 bb = f2b(a * cinv[v]);  // = A_b[v][w]
  Aops[idx] = f;
  supft[v * 1024 + w] = f;                // A_f^T[v][w]
  supbt[idx] = bb;                        // A_b^T[w][v]
  Aops[2 * 1048576 + v * 1024 + w] = bb;  // A_b[v][w]
}

// ---- setup: A^2 via bf16 MFMA: out[w][v] = sum_u A[w][u]*A[u][v] ------------
__global__ __launch_bounds__(256) void kA2(u16* Aops, const u16* supft, const u16* supbt) {
  int wg = blockIdx.x;  // 2 * 8 * 8 = 128
  int o2 = wg & 1, mt = (wg >> 1) & 7, ntt = (wg >> 4) & 7;
  const u16* Ab = Aops + (o2 ? 2 * 1048576 : 0);
  const u16* Bb = o2 ? supbt : supft;
  u16* Ob = Aops + (o2 ? 3 * 1048576 : 1048576);
  int tid = threadIdx.x, wave = tid >> 6, lane = tid & 63, l15 = lane & 15, quad = lane >> 4;
  int mbase = mt * 128 + wave * 32;
  f32x4 acc[2][8];
#pragma unroll
  for (int m = 0; m < 2; ++m)
#pragma unroll
    for (int j = 0; j < 8; ++j) acc[m][j] = (f32x4){0.f, 0.f, 0.f, 0.f};
  for (int k = 0; k < 1024; k += 32) {
    int kq = k + quad * 8;
    bf16x8 av[2], bv[8];
#pragma unroll
    for (int m = 0; m < 2; ++m) av[m] = ld8(Ab + (mbase + m * 16 + l15) * 1024 + kq);
#pragma unroll
    for (int j = 0; j < 8; ++j) bv[j] = ld8(Bb + (ntt * 128 + j * 16 + l15) * 1024 + kq);
#pragma unroll
    for (int m = 0; m < 2; ++m)
#pragma unroll
      for (int j = 0; j < 8; ++j) acc[m][j] = MFMA16(av[m], bv[j], acc[m][j]);
  }
#pragma unroll
  for (int m = 0; m < 2; ++m)
#pragma unroll
    for (int j = 0; j < 8; ++j) {
      int v = ntt * 128 + j * 16 + l15;
#pragma unroll
      for (int i = 0; i < 4; ++i) {
        int w = mbase + m * 16 + quad * 4 + i;
        Ob[w * 1024 + v] = f2b(acc[m][j][i]);
      }
    }
}

// ---- setup: pack weights to bf16, K=416 layout ------------------------------
__global__ __launch_bounds__(256) void kpackw(const float* Wr, const float* Wu, const float* Wc,
                                              u16* Wrup, u16* Wcp) {
  int idx = blockIdx.x * 256 + threadIdx.x;  // 192*416 = 79872
  int r = idx / KC, k = idx % KC;
  if (r >= 192) return;
  float wv = 0.f;
  if (k < 396) {
    int c = (k < 66) ? k : (k - 66);  // hi block: c=k; lo block + diffused: c=k-66
    if (r < 64) wv = Wr[r * 330 + c];
    else if (r < 128) wv = Wu[(r - 64) * 330 + c];
    else wv = Wc[(r - 128) * 330 + c];
  }
  if (r < 128) Wrup[r * KC + k] = f2b(wv);
  else Wcp[(r - 128) * KC + k] = f2b(wv);
}

// ---- setup: t=0 state, outputs, xh/xc init ----------------------------------
__global__ __launch_bounds__(256) void kstep0(const float* x, const int* mask, const float* bout,
                                              float* h, float* states, float* preds,
                                              u16* xh, u16* xc) {
  int wg = blockIdx.x;  // b*148 + row, 1184 blocks
  int b = wg / 148, row = wg - b * 148;
  int n = threadIdx.x * 4;
  for (int k = 0; k < 4; ++k, ++n) {
    u16 xhv = 0;
    if (row == 0 || row == 1 || row == 80) {
      int xi = (b * 1024 + n) * 128;
      int mv = mask[xi];
      float xhat = bout[0];  // Wout . 0 + bout
      float xin = mv ? x[xi] : xhat;
      u16 hi = f2b(xin);
      if (row == 0) { xhv = hi; preds[xi] = xhat; }
      else if (row == 1) xhv = f2b((float)mv);
      else xhv = f2b(xin - b2f(hi));
    }
    xh[(b * CP + row) * 1024 + n] = xhv;
    xc[(b * CP + row) * 1024 + n] = 0;
    if (row >= 2 && row < 66) {
      int o = row - 2;
      int idx = (b * 64 + o) * 1024 + n;
      h[idx] = 0.f;
      states[(size_t)idx * 128] = 0.f;  // states[t=0] = h0 = 0
    }
  }
}

// ---- phase A (fused): diffusion(xh) -> LDS; conv r,u; write ubuf, xc --------
// grid 256 = b*32 + nt (32 nodes/block); 8 waves: (op = w&3, khalf = w>>2)
__global__ __launch_bounds__(512, 1) void kphA(const u16* __restrict__ xh, const u16* __restrict__ Aops,
                                               const u16* __restrict__ Wrup,
                                               const float* br, const float* bu,
                                               const float* __restrict__ h, float* __restrict__ ubuf,
                                               u16* __restrict__ xc) {
  extern __shared__ char smem[];
  u16 (*zl)[KL] = (u16(*)[KL])smem;                 // [32][424]
  float* scr = (float*)(smem + ZLB);                // [4][64][44] f32
  int wg = blockIdx.x;
  int b = wg >> 5, nt = wg & 31;
  int n0 = nt * 32;
  int tid = threadIdx.x, w = tid >> 6, lane = tid & 63, l15 = lane & 15, quad = lane >> 4;
  int op = w & 3, kh = w >> 2;

  // stage direct channels: xh rows {0..65, 80..145} -> zl cols 0..131
  // (and copy x/mask rows straight through to xc for phase B)
  for (int i = tid; i < 2112; i += 512) {
    int ch = i >> 4, cp = i & 15;
    int srow = ch < 66 ? ch : ch + 14;
    u32 v = *(const u32*)(xh + (b * CP + srow) * 1024 + n0 + cp * 2);
    zl[cp * 2][ch] = (u16)v;
    zl[cp * 2 + 1][ch] = (u16)(v >> 16);
    if (ch == 0 || ch == 1 || ch == 66 || ch == 67)
      *(u32*)(xc + (b * CP + srow) * 1024 + n0 + cp * 2) = v;
  }
  for (int i = tid; i < 320; i += 512) {  // zero pad ch 396..415
    int n = i / 10, c = i - n * 10;
    ((u32*)zl[n])[198 + c] = 0;
  }

  // diffusion: out[ch][w] = sum_v Z[ch][v] * A_op[w][v]; fat 5x2 tile, K-half
  f32x4 dacc[5][2];
#pragma unroll
  for (int m = 0; m < 5; ++m)
#pragma unroll
    for (int j = 0; j < 2; ++j) dacc[m][j] = (f32x4){0.f, 0.f, 0.f, 0.f};
  {
    const u16* Zb = xh + b * CP * 1024;
    const u16* Ab = Aops + (op << 20);
    int kbase = kh << 9;
    for (int k = 0; k < 512; k += 32) {
      int kq = kbase + k + quad * 8;
      bf16x8 av[5], bv[2];
#pragma unroll
      for (int m = 0; m < 5; ++m) av[m] = ld8(Zb + (m * 16 + l15) * 1024 + kq);
#pragma unroll
      for (int j = 0; j < 2; ++j) bv[j] = ld8(Ab + (n0 + j * 16 + l15) * 1024 + kq);
#pragma unroll
      for (int m = 0; m < 5; ++m)
#pragma unroll
        for (int j = 0; j < 2; ++j) dacc[m][j] = MFMA16(av[m], bv[j], dacc[m][j]);
    }
  }
  if (kh) {  // high-K waves publish partials
    f32x4* s = (f32x4*)(scr + (op * 64 + lane) * 44);
#pragma unroll
    for (int m = 0; m < 5; ++m)
#pragma unroll
      for (int j = 0; j < 2; ++j) s[m * 2 + j] = dacc[m][j];
  }
  __syncthreads();  // B1
  if (!kh) {  // reduce + round to bf16 into zl diffused channels
    f32x4* s = (f32x4*)(scr + (op * 64 + lane) * 44);
    int cbase = 132 + op * 66;
#pragma unroll
    for (int m = 0; m < 5; ++m)
#pragma unroll
      for (int j = 0; j < 2; ++j) {
        f32x4 a = dacc[m][j] + s[m * 2 + j];
        u16* orow = zl[j * 16 + l15] + cbase;  // col = node
        int c0 = m * 16 + quad * 4;
        if (c0 < 64) {
          st2f(orow + c0, a[0], a[1]);
          st2f(orow + c0 + 2, a[2], a[3]);
        } else if (c0 == 64) {
          st2f(orow + 64, a[0], a[1]);
        }
      }
  }
  __syncthreads();  // B2: zl complete

  // conv r,u: [128 out x 416] x [32 nodes]; og = w&3 (32 outs), K-split by kh
  int og = w & 3, obase = og * 32;
  f32x4 cacc[2][2];
#pragma unroll
  for (int m = 0; m < 2; ++m)
#pragma unroll
    for (int j = 0; j < 2; ++j) cacc[m][j] = (f32x4){0.f, 0.f, 0.f, 0.f};
  {
    int k0 = kh ? 224 : 0, k1 = kh ? KC : 224;
    for (int k = k0; k < k1; k += 32) {
      int kq = k + quad * 8;
      bf16x8 av[2], bv[2];
#pragma unroll
      for (int m = 0; m < 2; ++m) av[m] = ld8(Wrup + (obase + m * 16 + l15) * KC + kq);
#pragma unroll
      for (int j = 0; j < 2; ++j) bv[j] = ld8(zl[j * 16 + l15] + kq);
#pragma unroll
      for (int m = 0; m < 2; ++m)
#pragma unroll
        for (int j = 0; j < 2; ++j) cacc[m][j] = MFMA16(av[m], bv[j], cacc[m][j]);
    }
  }
  if (kh) {
    f32x4* s = (f32x4*)(scr + (og * 64 + lane) * 44);
#pragma unroll
    for (int m = 0; m < 2; ++m)
#pragma unroll
      for (int j = 0; j < 2; ++j) s[m * 2 + j] = cacc[m][j];
  }
  __syncthreads();  // B3
  if (!kh) {  // reduce + epilogue
    f32x4* s = (f32x4*)(scr + (og * 64 + lane) * 44);
#pragma unroll
    for (int m = 0; m < 2; ++m)
#pragma unroll
      for (int j = 0; j < 2; ++j) {
        f32x4 a = cacc[m][j] + s[m * 2 + j];
        int o0 = obase + m * 16 + quad * 4;
        int n = n0 + j * 16 + l15;
        if (o0 < 64) {  // r gate -> r*h hi/lo into xc
#pragma unroll
          for (int i = 0; i < 4; ++i) {
            float sg = sigm(a[i] + br[o0 + i]);
            float rh = sg * h[(b * 64 + o0 + i) * 1024 + n];
            u16 hi = f2b(rh);
            xc[(b * CP + 2 + o0 + i) * 1024 + n] = hi;
            xc[(b * CP + 82 + o0 + i) * 1024 + n] = f2b(rh - b2f(hi));
          }
        } else {  // u gate
#pragma unroll
          for (int i = 0; i < 4; ++i)
            ubuf[(b * 64 + o0 - 64 + i) * 1024 + n] = sigm(a[i] + bu[o0 - 64 + i]);
        }
      }
  }
}

// ---- phase B (fused): diffusion(xc) -> LDS; conv c; h update; x_hat ---------
__global__ __launch_bounds__(512, 1) void kphB(const u16* __restrict__ xc, const u16* __restrict__ Aops,
                                               const u16* __restrict__ Wcp,
                                               const float* bc, const float* __restrict__ ubuf,
                                               float* __restrict__ h, const float* __restrict__ x,
                                               const int* __restrict__ mask, const float* Wout,
                                               const float* bout, float* __restrict__ preds,
                                               float* __restrict__ states, u16* __restrict__ xh,
                                               int t) {
  extern __shared__ char smem[];
  u16 (*yl)[KL] = (u16(*)[KL])smem;                 // [32][424]
  float* scr = (float*)(smem + ZLB);                // [4][64][44] f32
  float* hbuf = (float*)(smem + ZLB + SCRB);        // [64][33] f32
  int wg = blockIdx.x;
  int b = wg >> 5, nt = wg & 31;
  int n0 = nt * 32;
  int tid = threadIdx.x, w = tid >> 6, lane = tid & 63, l15 = lane & 15, quad = lane >> 4;
  int op = w & 3, kh = w >> 2;

  for (int i = tid; i < 2112; i += 512) {
    int ch = i >> 4, cp = i & 15;
    int srow = ch < 66 ? ch : ch + 14;
    u32 v = *(const u32*)(xc + (b * CP + srow) * 1024 + n0 + cp * 2);
    yl[cp * 2][ch] = (u16)v;
    yl[cp * 2 + 1][ch] = (u16)(v >> 16);
  }
  for (int i = tid; i < 320; i += 512) {
    int n = i / 10, c = i - n * 10;
    ((u32*)yl[n])[198 + c] = 0;
  }

  // diffusion of xc
  f32x4 dacc[5][2];
#pragma unroll
  for (int m = 0; m < 5; ++m)
#pragma unroll
    for (int j = 0; j < 2; ++j) dacc[m][j] = (f32x4){0.f, 0.f, 0.f, 0.f};
  {
    const u16* Zb = xc + b * CP * 1024;
    const u16* Ab = Aops + (op << 20);
    int kbase = kh << 9;
    for (int k = 0; k < 512; k += 32) {
      int kq = kbase + k + quad * 8;
      bf16x8 av[5], bv[2];
#pragma unroll
      for (int m = 0; m < 5; ++m) av[m] = ld8(Zb + (m * 16 + l15) * 1024 + kq);
#pragma unroll
      for (int j = 0; j < 2; ++j) bv[j] = ld8(Ab + (n0 + j * 16 + l15) * 1024 + kq);
#pragma unroll
      for (int m = 0; m < 5; ++m)
#pragma unroll
        for (int j = 0; j < 2; ++j) dacc[m][j] = MFMA16(av[m], bv[j], dacc[m][j]);
    }
  }
  if (kh) {
    f32x4* s = (f32x4*)(scr + (op * 64 + lane) * 44);
#pragma unroll
    for (int m = 0; m < 5; ++m)
#pragma unroll
      for (int j = 0; j < 2; ++j) s[m * 2 + j] = dacc[m][j];
  }
  __syncthreads();  // B1
  if (!kh) {
    f32x4* s = (f32x4*)(scr + (op * 64 + lane) * 44);
    int cbase = 132 + op * 66;
#pragma unroll
    for (int m = 0; m < 5; ++m)
#pragma unroll
      for (int j = 0; j < 2; ++j) {
        f32x4 a = dacc[m][j] + s[m * 2 + j];
        u16* orow = yl[j * 16 + l15] + cbase;
        int c0 = m * 16 + quad * 4;
        if (c0 < 64) {
          st2f(orow + c0, a[0], a[1]);
          st2f(orow + c0 + 2, a[2], a[3]);
        } else if (c0 == 64) {
          st2f(orow + 64, a[0], a[1]);
        }
      }
  }
  __syncthreads();  // B2

  // conv c: [64 out x 416] x [32 nodes]; task = (og = w&1, jg = (w>>1)&1), K-split
  int og = w & 1, jg = (w >> 1) & 1, task = w & 3;
  int obase = og * 32;
  f32x4 cacc[2];
  cacc[0] = (f32x4){0.f, 0.f, 0.f, 0.f};
  cacc[1] = (f32x4){0.f, 0.f, 0.f, 0.f};
  {
    int k0 = kh ? 224 : 0, k1 = kh ? KC : 224;
    for (int k = k0; k < k1; k += 32) {
      int kq = k + quad * 8;
      bf16x8 bv = ld8(yl[jg * 16 + l15] + kq);
      bf16x8 av0 = ld8(Wcp + (obase + l15) * KC + kq);
      bf16x8 av1 = ld8(Wcp + (obase + 16 + l15) * KC + kq);
      cacc[0] = MFMA16(av0, bv, cacc[0]);
      cacc[1] = MFMA16(av1, bv, cacc[1]);
    }
  }
  if (kh) {
    f32x4* s = (f32x4*)(scr + (task * 64 + lane) * 44);
    s[0] = cacc[0];
    s[1] = cacc[1];
  }
  __syncthreads();  // B3
  int t1 = t + 1;
  if (!kh) {  // reduce + h update
    f32x4* s = (f32x4*)(scr + (task * 64 + lane) * 44);
    int n = n0 + jg * 16 + l15, nloc = jg * 16 + l15;
#pragma unroll
    for (int m = 0; m < 2; ++m) {
      f32x4 a = cacc[m] + s[m];
      int o0 = obase + m * 16 + quad * 4;
#pragma unroll
      for (int i = 0; i < 4; ++i) {
        int o = o0 + i;
        float c = tanh_f(a[i] + bc[o]);
        int idx = (b * 64 + o) * 1024 + n;
        float u = ubuf[idx], hp = h[idx];
        float hn = u * hp + (1.f - u) * c;
        h[idx] = hn;
        hbuf[o * 33 + nloc] = hn;
        u16 hi = f2b(hn);
        if (t1 < Tt) {
          states[(size_t)idx * 128 + t1] = hn;
          xh[(b * CP + 2 + o) * 1024 + n] = hi;
          xh[(b * CP + 82 + o) * 1024 + n] = f2b(hn - b2f(hi));
        }
      }
    }
  }
  __syncthreads();  // B4
  if (tid < 32 && t1 < Tt) {
    int nn = n0 + tid;
    float xhat = bout[0];
#pragma unroll
    for (int o = 0; o < 64; ++o) xhat += Wout[o] * hbuf[o * 33 + tid];
    int xi = (b * 1024 + nn) * 128 + t1;
    int mv = mask[xi];
    float xin = mv ? x[xi] : xhat;
    preds[xi] = xhat;
    u16 hi2 = f2b(xin);
    xh[(b * CP + 0) * 1024 + nn] = hi2;
    xh[(b * CP + 1) * 1024 + nn] = f2b((float)mv);
    xh[(b * CP + 80) * 1024 + nn] = f2b(xin - b2f(hi2));
  }
}

extern "C" void kernel_launch(void* const* d_in, const int* in_sizes, int n_in,
                              void* d_out, int out_size, void* d_ws, size_t ws_size,
                              hipStream_t stream) {
  const float* x = (const float*)d_in[0];
  const int* mask = (const int*)d_in[1];
  const float* adj = (const float*)d_in[2];
  const float* Wr = (const float*)d_in[3];
  const float* br = (const float*)d_in[4];
  const float* Wu = (const float*)d_in[5];
  const float* bu = (const float*)d_in[6];
  const float* Wc = (const float*)d_in[7];
  const float* bc = (const float*)d_in[8];
  const float* Wout = (const float*)d_in[9];
  const float* bout = (const float*)d_in[10];

  float* preds = (float*)d_out;                  // [8,1,1024,128]
  float* states = preds + 8 * 1024 * 128;        // [1,8,64,1024,128]

  // workspace carve-up (bf16 buffers as u16; all MFMA-load bases 16B aligned)
  u16* Aops = (u16*)d_ws;                        // [4][1024][1024]
  u16* supft = Aops + 4 * 1048576;               // A_f^T
  u16* supbt = supft + 1048576;                  // A_b^T
  float* rinv = (float*)(supbt + 1048576);
  float* cinv = rinv + 1024;
  u16* xh = (u16*)(cinv + 1024);                 // [8][148][1024] phase-A operand
  u16* xc = xh + Bz * CP * 1024;                 // [8][148][1024] phase-B operand
  u16* Wrup = xc + Bz * CP * 1024;               // [128][416]
  u16* Wcp = Wrup + 128 * KC;                    // [64][416]
  float* ubuf = (float*)(Wcp + 64 * KC);         // [8][64][1024]
  float* h = ubuf + Bz * 64 * 1024;              // [8][64][1024]

  static int lds_set = 0;
  if (!lds_set) {  // allow >64KB dynamic LDS (gfx950 has 160KB/CU)
    hipFuncSetAttribute((const void*)kphA, hipFuncAttributeMaxDynamicSharedMemorySize, ZLB + SCRB);
    hipFuncSetAttribute((const void*)kphB, hipFuncAttributeMaxDynamicSharedMemorySize,
                        ZLB + SCRB + 64 * 33 * 4);
    lds_set = 1;
  }

  ksums<<<8, 256, 0, stream>>>(adj, rinv, cinv);
  kmakeops<<<4096, 256, 0, stream>>>(adj, rinv, cinv, Aops, supft, supbt);
  kA2<<<128, 256, 0, stream>>>(Aops, supft, supbt);
  kpackw<<<312, 256, 0, stream>>>(Wr, Wu, Wc, Wrup, Wcp);
  kstep0<<<1184, 256, 0, stream>>>(x, mask, bout, h, states, preds, xh, xc);

  for (int t = 0; t < Tt; ++t) {
    kphA<<<256, 512, ZLB + SCRB, stream>>>(xh, Aops, Wrup, br, bu, h, ubuf, xc);
    kphB<<<256, 512, ZLB + SCRB + 64 * 33 * 4, stream>>>(xc, Aops, Wcp, bc, ubuf, h, x, mask,
                                                         Wout, bout, preds, states, xh, t);
  }
}